// Round 1
// baseline (498.613 us; speedup 1.0000x reference)
//
#include <hip/hip_runtime.h>
#include <cmath>

#define N_TOK 8192
#define DIM   384
#define NEXP  8
#define HID   1536
#define OUTD  384
#define BM    64

typedef __attribute__((ext_vector_type(8)))  __bf16 bf16x8;
typedef __attribute__((ext_vector_type(16))) float  f32x16;

__device__ __forceinline__ unsigned short f2bf(float f) {
    unsigned u = __float_as_uint(f);
    u += 0x7FFF + ((u >> 16) & 1);          // round-to-nearest-even
    return (unsigned short)(u >> 16);
}

__device__ __forceinline__ float gelu_exact(float x) {
    return 0.5f * x * (1.0f + erff(x * 0.70710678118654752f));
}

// ---------------------------------------------------------------- init
__global__ void init_kernel(float* __restrict__ out, int* __restrict__ cnt) {
    int gid = blockIdx.x * blockDim.x + threadIdx.x;
    if (gid < NEXP) cnt[gid] = 0;
    float4* o4 = (float4*)out;
    const int n4 = N_TOK * OUTD / 4;
    for (int i = gid; i < n4; i += gridDim.x * blockDim.x)
        o4[i] = make_float4(0.f, 0.f, 0.f, 0.f);
}

// ---------------------------------------------------------------- x -> bf16
__global__ void cvt_x_kernel(const float* __restrict__ x, unsigned short* __restrict__ xb) {
    int i = blockIdx.x * blockDim.x + threadIdx.x;
    const int n4 = N_TOK * DIM / 4;
    if (i < n4) {
        float4 v = ((const float4*)x)[i];
        ushort4 r;
        r.x = f2bf(v.x); r.y = f2bf(v.y); r.z = f2bf(v.z); r.w = f2bf(v.w);
        ((ushort4*)xb)[i] = r;
    }
}

// ------------------------------------------------- W[e][R][C] -> Wt[e][C][R] (bf16)
__global__ void transpose_bf16_kernel(const float* __restrict__ src,
                                      unsigned short* __restrict__ dst,
                                      int R, int C) {
    __shared__ float tile[32][33];
    int e  = blockIdx.z;
    int c0 = blockIdx.x * 32;
    int r0 = blockIdx.y * 32;
    const float* s = src + (size_t)e * R * C;
    unsigned short* d = dst + (size_t)e * R * C;
    int tx = threadIdx.x & 31, ty = threadIdx.x >> 5;   // 32 x 8
    #pragma unroll
    for (int i = 0; i < 32; i += 8)
        tile[ty + i][tx] = s[(size_t)(r0 + ty + i) * C + c0 + tx];
    __syncthreads();
    #pragma unroll
    for (int i = 0; i < 32; i += 8)
        d[(size_t)(c0 + ty + i) * R + r0 + tx] = f2bf(tile[tx][ty + i]);
}

// ---------------------------------------------------------------- router
__global__ void router_kernel(const float* __restrict__ x, const float* __restrict__ Wg,
                              const float* __restrict__ bg, int* __restrict__ cnt,
                              int* __restrict__ btok, float* __restrict__ bgate) {
    __shared__ float WgL[DIM * NEXP];           // 12 KB
    int tid = threadIdx.x;
    for (int i = tid; i < DIM * NEXP; i += 256) WgL[i] = Wg[i];
    __syncthreads();

    int t = blockIdx.x * 256 + tid;             // token id
    float lg[NEXP];
    #pragma unroll
    for (int e = 0; e < NEXP; ++e) lg[e] = bg[e];

    const float4* xr = (const float4*)(x + (size_t)t * DIM);
    for (int d4 = 0; d4 < DIM / 4; ++d4) {
        float4 v = xr[d4];
        const float* wrow = &WgL[d4 * 4 * NEXP];
        #pragma unroll
        for (int e = 0; e < NEXP; ++e)
            lg[e] += v.x * wrow[e] + v.y * wrow[NEXP + e]
                   + v.z * wrow[2 * NEXP + e] + v.w * wrow[3 * NEXP + e];
    }

    // top-2, ties -> lower index (matches jax.lax.top_k)
    float v0 = -INFINITY, v1 = -INFINITY; int i0 = 0, i1 = 0;
    #pragma unroll
    for (int e = 0; e < NEXP; ++e) {
        float v = lg[e];
        if (v > v0)      { v1 = v0; i1 = i0; v0 = v; i0 = e; }
        else if (v > v1) { v1 = v;  i1 = e; }
    }
    // softmax over the two selected logits (others are -inf -> 0)
    float e1 = expf(v1 - v0);
    float g0 = 1.f / (1.f + e1);
    float g1 = e1  / (1.f + e1);

    int p0 = atomicAdd(&cnt[i0], 1);
    btok[i0 * N_TOK + p0]  = t;
    bgate[i0 * N_TOK + p0] = g0;
    int p1 = atomicAdd(&cnt[i1], 1);
    btok[i1 * N_TOK + p1]  = t;
    bgate[i1 * N_TOK + p1] = g1;
}

// ---------------------------------------------------------------- fused expert MLP
// grid (128, NEXP), 256 threads (4 waves). Per block: 64 gathered tokens of expert e.
// GEMM1: h[64][64chunk] = x[64][384] @ W1t^T ; gelu ; GEMM2: y += h @ W2 chunk.
// mfma_f32_32x32x16_bf16: A[m=l&31][k=(l>>5)*8+j], B[k=(l>>5)*8+j][n=l&31],
// C/D: col=l&31, row=(r&3)+8*(r>>2)+4*(l>>5).
__global__ __launch_bounds__(256, 2) void expert_kernel(
        const unsigned short* __restrict__ xb,  const unsigned short* __restrict__ w1t,
        const unsigned short* __restrict__ w2t, const float* __restrict__ b1,
        const float* __restrict__ b2,           const int* __restrict__ cnt,
        const int* __restrict__ btok,           const float* __restrict__ bgate,
        float* __restrict__ out) {
    int e    = blockIdx.y;
    int cntE = cnt[e];
    int base = blockIdx.x * BM;
    if (base >= cntE) return;
    int nvalid = min(BM, cntE - base);

    __shared__ unsigned short x_lds[BM * 392];   // 384 + 8 pad, 16B-aligned rows
    __shared__ unsigned short h_lds[BM * 72];    // 64 + 8 pad
    __shared__ int   tokL[BM];
    __shared__ float gateL[BM];

    int tid = threadIdx.x;
    if (tid < BM) {
        int idx   = (tid < nvalid) ? base + tid : base;   // clamp pad rows
        tokL[tid]  = btok[e * N_TOK + idx];
        gateL[tid] = bgate[e * N_TOK + idx];
    }
    __syncthreads();

    { // stage gathered x rows into LDS (bf16), 16B chunks, 4 threads per row
        int row = tid >> 2, q = tid & 3;
        const unsigned short* src = xb + (size_t)tokL[row] * DIM;
        #pragma unroll
        for (int it = 0; it < 12; ++it) {
            int c = q + it * 4;   // 48 x 16B per row
            *(uint4*)(&x_lds[row * 392 + c * 8]) = *(const uint4*)(src + c * 8);
        }
    }
    __syncthreads();

    int wave = tid >> 6, lane = tid & 63;
    int m31 = lane & 31, kh = lane >> 5;
    int Mt = wave & 1, Wq = wave >> 1;   // GEMM1: Ht = Wq ; GEMM2: O-half = Wq

    f32x16 acc2[6];
    #pragma unroll
    for (int i = 0; i < 6; ++i)
        acc2[i] = (f32x16){0.f,0.f,0.f,0.f,0.f,0.f,0.f,0.f,0.f,0.f,0.f,0.f,0.f,0.f,0.f,0.f};

    const unsigned short* w1base = w1t + ((size_t)e * HID + Wq * 32 + m31) * DIM + kh * 8;
    const unsigned short* w2base = w2t + ((size_t)e * OUTD + Wq * 192 + m31) * HID + kh * 8;
    const unsigned short* xrow = &x_lds[(Mt * 32 + m31) * 392 + kh * 8];
    const unsigned short* hrow = &h_lds[(Mt * 32 + m31) * 72 + kh * 8];

    for (int hc = 0; hc < HID / 64; ++hc) {
        // ---- GEMM1: h[64][64] chunk, K = 384
        f32x16 acc1 = (f32x16){0.f,0.f,0.f,0.f,0.f,0.f,0.f,0.f,0.f,0.f,0.f,0.f,0.f,0.f,0.f,0.f};
        const unsigned short* wp = w1base + (size_t)hc * 64 * DIM;
        #pragma unroll 6
        for (int ks = 0; ks < 24; ++ks) {
            bf16x8 a = *(const bf16x8*)(xrow + ks * 16);
            bf16x8 b = *(const bf16x8*)(wp + ks * 16);
            acc1 = __builtin_amdgcn_mfma_f32_32x32x16_bf16(a, b, acc1, 0, 0, 0);
        }
        // ---- bias + exact gelu -> h_lds (bf16)
        float b1v = b1[e * HID + hc * 64 + Wq * 32 + m31];
        #pragma unroll
        for (int r = 0; r < 16; ++r) {
            int row = Mt * 32 + (r & 3) + 8 * (r >> 2) + 4 * kh;
            float v = gelu_exact(acc1[r] + b1v);
            h_lds[row * 72 + Wq * 32 + m31] = f2bf(v);
        }
        __syncthreads();
        // ---- GEMM2: y[64][384] += h[64][64] @ W2chunk, K = 64
        const unsigned short* w2p = w2base + hc * 64;
        #pragma unroll
        for (int ks = 0; ks < 4; ++ks) {
            bf16x8 a = *(const bf16x8*)(hrow + ks * 16);
            #pragma unroll
            for (int ot = 0; ot < 6; ++ot) {
                bf16x8 b = *(const bf16x8*)(w2p + (size_t)ot * 32 * HID + ks * 16);
                acc2[ot] = __builtin_amdgcn_mfma_f32_32x32x16_bf16(a, b, acc2[ot], 0, 0, 0);
            }
        }
        __syncthreads();   // h_lds reused next chunk
    }

    // ---- epilogue: out[tok][o] += gate * (y + b2)   (2 commutative adds/elem)
    #pragma unroll
    for (int ot = 0; ot < 6; ++ot) {
        int o = Wq * 192 + ot * 32 + m31;
        float b2v = b2[e * OUTD + o];
        #pragma unroll
        for (int r = 0; r < 16; ++r) {
            int row = Mt * 32 + (r & 3) + 8 * (r >> 2) + 4 * kh;
            if (row < nvalid) {
                float val = (acc2[ot][r] + b2v) * gateL[row];
                unsafeAtomicAdd(&out[(size_t)tokL[row] * OUTD + o], val);
            }
        }
    }
}

// ---------------------------------------------------------------- launch
extern "C" void kernel_launch(void* const* d_in, const int* in_sizes, int n_in,
                              void* d_out, int out_size, void* d_ws, size_t ws_size,
                              hipStream_t stream) {
    const float* x  = (const float*)d_in[0];
    const float* Wg = (const float*)d_in[1];
    const float* bg = (const float*)d_in[2];
    const float* W1 = (const float*)d_in[3];
    const float* b1 = (const float*)d_in[4];
    const float* W2 = (const float*)d_in[5];
    const float* b2 = (const float*)d_in[6];
    float* out = (float*)d_out;

    char* ws = (char*)d_ws;
    int*            cnt   = (int*)ws;                                  // 32 B
    int*            btok  = (int*)(ws + 256);                          // 256 KB
    float*          bgate = (float*)(ws + 256 + 262144);               // 256 KB
    unsigned short* xb    = (unsigned short*)(ws + 524544);            // 6.29 MB
    unsigned short* w1t   = (unsigned short*)(ws + 6816000);           // 9.44 MB
    unsigned short* w2t   = (unsigned short*)(ws + 16253184);          // 9.44 MB -> end ~24.5 MB

    hipLaunchKernelGGL(init_kernel, dim3(1024), dim3(256), 0, stream, out, cnt);
    hipLaunchKernelGGL(cvt_x_kernel, dim3(N_TOK * DIM / 4 / 256), dim3(256), 0, stream, x, xb);
    hipLaunchKernelGGL(transpose_bf16_kernel, dim3(HID / 32, DIM / 32, NEXP), dim3(256), 0, stream, W1, w1t, DIM, HID);
    hipLaunchKernelGGL(transpose_bf16_kernel, dim3(OUTD / 32, HID / 32, NEXP), dim3(256), 0, stream, W2, w2t, HID, OUTD);
    hipLaunchKernelGGL(router_kernel, dim3(N_TOK / 256), dim3(256), 0, stream, x, Wg, bg, cnt, btok, bgate);
    hipLaunchKernelGGL(expert_kernel, dim3(128, NEXP), dim3(256), 0, stream,
                       xb, w1t, w2t, b1, b2, cnt, btok, bgate, out);
}

// Round 2
// 330.473 us; speedup vs baseline: 1.5088x; 1.5088x over previous
//
#include <hip/hip_runtime.h>
#include <cmath>

#define N_TOK 8192
#define DIM   384
#define NEXP  8
#define HID   1536
#define OUTD  384
#define BM    64

typedef __attribute__((ext_vector_type(8)))  __bf16 bf16x8;
typedef __attribute__((ext_vector_type(16))) float  f32x16;

__device__ __forceinline__ unsigned short f2bf(float f) {
    unsigned u = __float_as_uint(f);
    u += 0x7FFF + ((u >> 16) & 1);          // round-to-nearest-even
    return (unsigned short)(u >> 16);
}

__device__ __forceinline__ float gelu_exact(float x) {
    return 0.5f * x * (1.0f + erff(x * 0.70710678118654752f));
}

// ---------------------------------------------------------------- init
__global__ void init_kernel(float* __restrict__ out, int* __restrict__ cnt) {
    int gid = blockIdx.x * blockDim.x + threadIdx.x;
    if (gid < NEXP) cnt[gid] = 0;
    float4* o4 = (float4*)out;
    const int n4 = N_TOK * OUTD / 4;
    for (int i = gid; i < n4; i += gridDim.x * blockDim.x)
        o4[i] = make_float4(0.f, 0.f, 0.f, 0.f);
}

// ---------------------------------------------------------------- x -> bf16
__global__ void cvt_x_kernel(const float* __restrict__ x, unsigned short* __restrict__ xb) {
    int i = blockIdx.x * blockDim.x + threadIdx.x;
    const int n4 = N_TOK * DIM / 4;
    if (i < n4) {
        float4 v = ((const float4*)x)[i];
        ushort4 r;
        r.x = f2bf(v.x); r.y = f2bf(v.y); r.z = f2bf(v.z); r.w = f2bf(v.w);
        ((ushort4*)xb)[i] = r;
    }
}

// ------------------------------------------------- W[e][K][N] fp32 -> B-fragment order bf16
// dst[((e*NT + nt)*KT + kt)*64 + l][j] = bf16(src[e][kt*16 + (l>>5)*8 + j][nt*32 + (l&31)])
// One thread per (e,nt,kt,lane); reads are 128B-contiguous across lanes, writes fully coalesced.
__global__ void swizzle_kernel(const float* __restrict__ src, unsigned short* __restrict__ dst,
                               int K, int N, int NT, int KT) {
    int gid = blockIdx.x * blockDim.x + threadIdx.x;
    int total = NEXP * NT * KT * 64;
    if (gid >= total) return;
    int l  = gid & 63;
    int kt = (gid >> 6) % KT;
    int nt = ((gid >> 6) / KT) % NT;
    int e  = gid / (64 * KT * NT);
    const float* s = src + ((size_t)e * K + kt * 16 + (l >> 5) * 8) * N + nt * 32 + (l & 31);
    unsigned short r[8];
    #pragma unroll
    for (int j = 0; j < 8; ++j) r[j] = f2bf(s[(size_t)j * N]);
    *(uint4*)(dst + (size_t)gid * 8) = *(uint4*)r;
}

// ---------------------------------------------------------------- router (LDS-aggregated)
__global__ void router_kernel(const float* __restrict__ x, const float* __restrict__ Wg,
                              const float* __restrict__ bg, int* __restrict__ cnt,
                              int* __restrict__ btok, float* __restrict__ bgate) {
    __shared__ float WgL[DIM * NEXP];           // 12 KB
    __shared__ int lcnt[NEXP];
    __shared__ int lbase[NEXP];
    int tid = threadIdx.x;
    for (int i = tid; i < DIM * NEXP; i += 256) WgL[i] = Wg[i];
    if (tid < NEXP) lcnt[tid] = 0;
    __syncthreads();

    int t = blockIdx.x * 256 + tid;             // token id
    float lg[NEXP];
    #pragma unroll
    for (int e = 0; e < NEXP; ++e) lg[e] = bg[e];

    const float4* xr = (const float4*)(x + (size_t)t * DIM);
    for (int d4 = 0; d4 < DIM / 4; ++d4) {
        float4 v = xr[d4];
        const float* wrow = &WgL[d4 * 4 * NEXP];
        #pragma unroll
        for (int e = 0; e < NEXP; ++e)
            lg[e] += v.x * wrow[e] + v.y * wrow[NEXP + e]
                   + v.z * wrow[2 * NEXP + e] + v.w * wrow[3 * NEXP + e];
    }

    // top-2, ties -> lower index (matches jax.lax.top_k)
    float v0 = -INFINITY, v1 = -INFINITY; int i0 = 0, i1 = 0;
    #pragma unroll
    for (int e = 0; e < NEXP; ++e) {
        float v = lg[e];
        if (v > v0)      { v1 = v0; i1 = i0; v0 = v; i0 = e; }
        else if (v > v1) { v1 = v;  i1 = e; }
    }
    float e1 = expf(v1 - v0);
    float g0 = 1.f / (1.f + e1);
    float g1 = e1  / (1.f + e1);

    int p0 = atomicAdd(&lcnt[i0], 1);
    int p1 = atomicAdd(&lcnt[i1], 1);
    __syncthreads();
    if (tid < NEXP) lbase[tid] = atomicAdd(&cnt[tid], lcnt[tid]);
    __syncthreads();
    int o0 = lbase[i0] + p0, o1 = lbase[i1] + p1;
    btok[i0 * N_TOK + o0]  = t;  bgate[i0 * N_TOK + o0] = g0;
    btok[i1 * N_TOK + o1]  = t;  bgate[i1 * N_TOK + o1] = g1;
}

// ---------------------------------------------------------------- fused expert MLP
// grid (128, NEXP), 256 threads (4 waves). Per block: 64 gathered tokens of expert e.
// Weights pre-swizzled to B-fragment order: every load = coalesced 1KB dwordx4.
// x staged in A-fragment order in LDS: conflict-free ds_read_b128.
// mfma_f32_32x32x16_bf16: A[m=l&31][k=(l>>5)*8+j], B[k=(l>>5)*8+j][n=l&31],
// C/D: col=l&31, row=(r&3)+8*(r>>2)+4*(l>>5).
__global__ __launch_bounds__(256, 2) void expert_kernel(
        const unsigned short* __restrict__ xb,  const unsigned short* __restrict__ w1s,
        const unsigned short* __restrict__ w2s, const float* __restrict__ b1,
        const float* __restrict__ b2,           const int* __restrict__ cnt,
        const int* __restrict__ btok,           const float* __restrict__ bgate,
        float* __restrict__ out) {
    int e    = blockIdx.y;
    int cntE = cnt[e];
    int base = blockIdx.x * BM;
    if (base >= cntE) return;
    int nvalid = min(BM, cntE - base);

    __shared__ unsigned short x_frag[2 * 24 * 64 * 8];   // 48 KB, A-fragment order
    __shared__ unsigned short h_lds[BM * 72];            // 9 KB, row-major +8 pad
    __shared__ int   tokL[BM];
    __shared__ float gateL[BM];

    int tid = threadIdx.x;
    if (tid < BM) {
        int idx   = (tid < nvalid) ? base + tid : base;   // clamp pad rows
        tokL[tid]  = btok[e * N_TOK + idx];
        gateL[tid] = bgate[e * N_TOK + idx];
    }
    __syncthreads();

    { // stage gathered x rows into LDS in A-fragment order
        int r = tid >> 2, q = tid & 3;
        const unsigned short* src = xb + (size_t)tokL[r] * DIM;
        int mt = r >> 5, m = r & 31;
        #pragma unroll
        for (int i = 0; i < 12; ++i) {
            int c = q + i * 4;          // 16B chunk along K, 0..47
            int kt = c >> 1, kh = c & 1;
            *(uint4*)&x_frag[(((mt * 24 + kt) * 64) + kh * 32 + m) * 8] =
                *(const uint4*)(src + c * 8);
        }
    }
    __syncthreads();

    int wave = tid >> 6, lane = tid & 63;
    int m31 = lane & 31, kh = lane >> 5;
    int Mt = wave & 1, Wq = wave >> 1;

    f32x16 acc2[6];
    #pragma unroll
    for (int i = 0; i < 6; ++i)
        acc2[i] = (f32x16){0.f,0.f,0.f,0.f,0.f,0.f,0.f,0.f,0.f,0.f,0.f,0.f,0.f,0.f,0.f,0.f};

    const unsigned short* w1e = w1s + (size_t)e * 48 * 24 * 512;   // [nt][kt][l*8]
    const unsigned short* w2e = w2s + (size_t)e * 12 * 96 * 512;   // [nt][kt][l*8]
    const unsigned short* xr  = &x_frag[(size_t)Mt * 24 * 512 + lane * 8];
    const unsigned short* hrow = &h_lds[(Mt * 32 + m31) * 72 + kh * 8];

    for (int hc = 0; hc < HID / 64; ++hc) {
        // ---- GEMM1: h[64][64] chunk, K = 384
        f32x16 acc1 = (f32x16){0.f,0.f,0.f,0.f,0.f,0.f,0.f,0.f,0.f,0.f,0.f,0.f,0.f,0.f,0.f,0.f};
        const unsigned short* wp = w1e + ((size_t)(hc * 2 + Wq) * 24) * 512 + lane * 8;
        #pragma unroll 8
        for (int ks = 0; ks < 24; ++ks) {
            bf16x8 a = *(const bf16x8*)(xr + ks * 512);
            bf16x8 b = *(const bf16x8*)(wp + ks * 512);
            acc1 = __builtin_amdgcn_mfma_f32_32x32x16_bf16(a, b, acc1, 0, 0, 0);
        }
        // ---- bias + exact gelu -> h_lds (bf16)
        float b1v = b1[e * HID + hc * 64 + Wq * 32 + m31];
        #pragma unroll
        for (int r = 0; r < 16; ++r) {
            int row = Mt * 32 + (r & 3) + 8 * (r >> 2) + 4 * kh;
            float v = gelu_exact(acc1[r] + b1v);
            h_lds[row * 72 + Wq * 32 + m31] = f2bf(v);
        }
        __syncthreads();
        // ---- GEMM2: y[64][384] += h[64][64] @ W2chunk, K = 64
        #pragma unroll
        for (int ks = 0; ks < 4; ++ks) {
            bf16x8 a = *(const bf16x8*)(hrow + ks * 16);
            #pragma unroll
            for (int ot = 0; ot < 6; ++ot) {
                const unsigned short* w2p = w2e + ((size_t)(Wq * 6 + ot) * 96 + hc * 4 + ks) * 512;
                bf16x8 b = *(const bf16x8*)(w2p + lane * 8);
                acc2[ot] = __builtin_amdgcn_mfma_f32_32x32x16_bf16(a, b, acc2[ot], 0, 0, 0);
            }
        }
        __syncthreads();   // h_lds reused next chunk
    }

    // ---- epilogue: out[tok][o] += gate * (y + b2)   (2 commutative adds/elem)
    #pragma unroll
    for (int ot = 0; ot < 6; ++ot) {
        int o = Wq * 192 + ot * 32 + m31;
        float b2v = b2[e * OUTD + o];
        #pragma unroll
        for (int r = 0; r < 16; ++r) {
            int row = Mt * 32 + (r & 3) + 8 * (r >> 2) + 4 * kh;
            if (row < nvalid) {
                float val = (acc2[ot][r] + b2v) * gateL[row];
                unsafeAtomicAdd(&out[(size_t)tokL[row] * OUTD + o], val);
            }
        }
    }
}

// ---------------------------------------------------------------- launch
extern "C" void kernel_launch(void* const* d_in, const int* in_sizes, int n_in,
                              void* d_out, int out_size, void* d_ws, size_t ws_size,
                              hipStream_t stream) {
    const float* x  = (const float*)d_in[0];
    const float* Wg = (const float*)d_in[1];
    const float* bg = (const float*)d_in[2];
    const float* W1 = (const float*)d_in[3];
    const float* b1 = (const float*)d_in[4];
    const float* W2 = (const float*)d_in[5];
    const float* b2 = (const float*)d_in[6];
    float* out = (float*)d_out;

    char* ws = (char*)d_ws;
    int*            cnt   = (int*)ws;                                  // 32 B
    int*            btok  = (int*)(ws + 256);                          // 256 KB
    float*          bgate = (float*)(ws + 256 + 262144);               // 256 KB
    unsigned short* xb    = (unsigned short*)(ws + 524544);            // 6.29 MB
    unsigned short* w1s   = (unsigned short*)(ws + 6816000);           // 9.44 MB
    unsigned short* w2s   = (unsigned short*)(ws + 16253184);          // 9.44 MB -> end ~24.5 MB

    hipLaunchKernelGGL(init_kernel, dim3(1024), dim3(256), 0, stream, out, cnt);
    hipLaunchKernelGGL(cvt_x_kernel, dim3(N_TOK * DIM / 4 / 256), dim3(256), 0, stream, x, xb);
    // W1: K=DIM, N=HID -> NT=48, KT=24 ; W2: K=HID, N=OUTD -> NT=12, KT=96
    hipLaunchKernelGGL(swizzle_kernel, dim3(NEXP * 48 * 24 * 64 / 256), dim3(256), 0, stream,
                       W1, w1s, DIM, HID, 48, 24);
    hipLaunchKernelGGL(swizzle_kernel, dim3(NEXP * 12 * 96 * 64 / 256), dim3(256), 0, stream,
                       W2, w2s, HID, OUTD, 12, 96);
    hipLaunchKernelGGL(router_kernel, dim3(N_TOK / 256), dim3(256), 0, stream, x, Wg, bg, cnt, btok, bgate);
    hipLaunchKernelGGL(expert_kernel, dim3(128, NEXP), dim3(256), 0, stream,
                       xb, w1s, w2s, b1, b2, cnt, btok, bgate, out);
}